// Round 6
// baseline (210.130 us; speedup 1.0000x reference)
//
#include <hip/hip_runtime.h>

#define HW    3136   // 56*56
#define KK    196
#define BCN   256    // B*C
#define KT    7      // k's per main block
#define NKC   28     // KK / KT
#define NSEG  49     // hw segments of 64
#define REP   8      // diagnostic in-kernel repeat (last rep == real pass)
#define LOG2E 1.4426950408889634f
// u prescale: log2(e) * 2^23 (Schraudolph domain)
#define PRESCALE (1.4426950408889634f * 8388608.0f)
// centered Schraudolph bias: 127*2^23 - 299487  (max rel err ~ +/-3.6%)
#define SCH_BIAS 1065053729.0f

// ---- Kernel 1: fused prep. Blocks [0,784): transpose+prescale u -> uT2[hw/2][bc].
//                Blocks [784,1127): repack rfs[hw][k] -> rfsT[kc][hw][KT].
__global__ __launch_bounds__(256) void rf_prep(const float* __restrict__ u,
                                               const float* __restrict__ rfs,
                                               float2* __restrict__ uT2,
                                               float* __restrict__ rfsT) {
    const int b = blockIdx.x;
    const int t = threadIdx.x;
    if (b < 784) {
        __shared__ float tile[16][65];
        const int h0 = (b % 49) * 64;     // hw tile
        const int b0 = (b / 49) * 16;     // bc tile
        const int c  = t & 63;
        const int r  = t >> 6;            // 0..3
        #pragma unroll
        for (int j = 0; j < 4; ++j)
            tile[r + 4*j][c] = u[(b0 + r + 4*j) * HW + h0 + c] * PRESCALE;
        __syncthreads();
        const int tw  = t & 15;           // bc within tile
        const int hp0 = t >> 4;           // 0..15
        #pragma unroll
        for (int i = 0; i < 2; ++i) {
            const int hp = hp0 + 16 * i;  // 0..31
            float2 v;
            v.x = tile[tw][2*hp];
            v.y = tile[tw][2*hp + 1];
            uT2[(size_t)(h0/2 + hp) * BCN + b0 + tw] = v;
        }
    } else {
        const int idx = (b - 784) * 256 + t;   // kc*HW + hw  (28*3136 = 343*256 exact)
        if (idx < NKC * HW) {
            const int kc = idx / HW;
            const int hw = idx % HW;
            const float* s = rfs + (size_t)hw * KK + kc * KT;
            float* d = rfsT + (size_t)idx * KT;
            #pragma unroll
            for (int j = 0; j < KT; ++j) d[j] = s[j];
        }
    }
}

// ---- Kernel 2: main (DIAGNOSTIC REP=8). grid (49 seg, 28 kc), block 256 (lane = bc).
// Inner math identical to R5. Opaque pointers per rep force real re-execution;
// only the last rep stores, producing bit-identical results to a single pass.
__global__ __launch_bounds__(256) void rf_main(const float2* __restrict__ uT2,
                                               const float* __restrict__ rfsT,
                                               float* __restrict__ part) {
    const int seg = blockIdx.x;            // 0..48
    const int kc  = blockIdx.y;            // 0..27
    const int t   = threadIdx.x;           // bc
    const int h0  = seg * 64;

    const float2* up0 = uT2 + (size_t)(h0/2) * BCN + t;
    const float*  rp0 = rfsT + ((size_t)kc * HW + h0) * KT;   // wave-uniform, contiguous

    for (int rep = 0; rep < REP; ++rep) {
        const float2* up = up0;
        const float*  rp = rp0;
        asm volatile("" : "+v"(up));   // per-lane address: keep in VGPR, opaque
        asm volatile("" : "+s"(rp));   // wave-uniform address: keep in SGPR, opaque

        float acc[KT][2];
        #pragma unroll
        for (int j = 0; j < KT; ++j) { acc[j][0] = 0.f; acc[j][1] = 0.f; }

        #pragma unroll 4
        for (int hp = 0; hp < 32; ++hp) {
            const float2 uv = up[(size_t)hp * BCN];
            #pragma unroll
            for (int j = 0; j < KT; ++j) {
                const float r0 = rp[(2*hp)     * KT + j];
                const float r1 = rp[(2*hp + 1) * KT + j];
                acc[j][0] += __int_as_float((int)fmaf(uv.x, r0, SCH_BIAS));
                acc[j][1] += __int_as_float((int)fmaf(uv.y, r1, SCH_BIAS));
            }
        }

        if (rep == REP - 1) {
            float* pp = part + (size_t)(kc * NSEG + seg) * KT * BCN + t;
            #pragma unroll
            for (int j = 0; j < KT; ++j)
                pp[j * BCN] = acc[j][0] + acc[j][1];
        } else {
            #pragma unroll
            for (int j = 0; j < KT; ++j)
                asm volatile("" :: "v"(acc[j][0]), "v"(acc[j][1]));
        }
    }
}

// ---- Kernel 3: reduce 49 segments, p = S/(1+S).
__global__ __launch_bounds__(256) void rf_fin(const float* __restrict__ part,
                                              float* __restrict__ out) {
    const int k = blockIdx.x;    // 0..195
    const int t = threadIdx.x;   // bc
    const int kc = k / KT;
    const int j  = k % KT;
    const float* pb = part + ((size_t)kc * NSEG * KT + j) * BCN + t;
    float s = 0.f;
    #pragma unroll
    for (int sg = 0; sg < NSEG; ++sg)
        s += pb[(size_t)sg * KT * BCN];
    out[(size_t)t * KK + k] = s / (1.0f + s);
}

// ---- Fallback (no workspace): monolithic, lane = k. Known-correct path (real exp2).
__global__ __launch_bounds__(256) void rf_pool_fallback(const float* __restrict__ u,
                                                        const float* __restrict__ rfs,
                                                        float* __restrict__ out) {
    const int grp = blockIdx.x;
    const int tid = threadIdx.x;
    const int bc0 = grp * 8;
    __shared__ __align__(16) float u_lds[8][196];
    float sum[8];
    #pragma unroll
    for (int g = 0; g < 8; ++g) sum[g] = 0.0f;
    for (int base = 0; base < HW; base += 196) {
        __syncthreads();
        if (tid < 196) {
            #pragma unroll
            for (int g = 0; g < 8; ++g)
                u_lds[g][tid] = u[(bc0 + g) * HW + base + tid] * LOG2E;
        }
        __syncthreads();
        if (tid < KK) {
            const float* rp = rfs + (size_t)base * KK + tid;
            for (int h = 0; h < 196; h += 4) {
                float rf0 = rp[(h + 0) * KK];
                float rf1 = rp[(h + 1) * KK];
                float rf2 = rp[(h + 2) * KK];
                float rf3 = rp[(h + 3) * KK];
                #pragma unroll
                for (int g = 0; g < 8; ++g) {
                    float4 ug = *(const float4*)&u_lds[g][h];
                    sum[g] += __builtin_amdgcn_exp2f(ug.x * rf0);
                    sum[g] += __builtin_amdgcn_exp2f(ug.y * rf1);
                    sum[g] += __builtin_amdgcn_exp2f(ug.z * rf2);
                    sum[g] += __builtin_amdgcn_exp2f(ug.w * rf3);
                }
            }
        }
    }
    if (tid < KK) {
        #pragma unroll
        for (int g = 0; g < 8; ++g) {
            float s = sum[g];
            out[(size_t)(bc0 + g) * KK + tid] = s / (s + 1.0f);
        }
    }
}

extern "C" void kernel_launch(void* const* d_in, const int* in_sizes, int n_in,
                              void* d_out, int out_size, void* d_ws, size_t ws_size,
                              hipStream_t stream) {
    const float* u   = (const float*)d_in[0];   // (8,32,56,56) f32
    const float* rfs = (const float*)d_in[1];   // (56,56,196) f32
    float* out = (float*)d_out;                 // (8,32,196) f32

    const size_t uT2_off  = 0;                       // 3.2 MB
    const size_t rfsT_off = 4u << 20;                // @4 MB, 2.46 MB
    const size_t part_off = 8u << 20;                // @8 MB, 9.84 MB
    const size_t need     = part_off + (size_t)NKC * NSEG * KT * BCN * sizeof(float);
    if (ws_size >= need) {
        float2* uT2  = (float2*)((char*)d_ws + uT2_off);
        float*  rfsT = (float*)((char*)d_ws + rfsT_off);
        float*  part = (float*)((char*)d_ws + part_off);
        rf_prep<<<784 + 343, 256, 0, stream>>>(u, rfs, uT2, rfsT);
        rf_main<<<dim3(NSEG, NKC), 256, 0, stream>>>(uT2, rfsT, part);
        rf_fin<<<KK, 256, 0, stream>>>(part, out);
    } else {
        rf_pool_fallback<<<BCN / 8, 256, 0, stream>>>(u, rfs, out);
    }
}

// Round 7
// 32.977 us; speedup vs baseline: 6.3721x; 6.3721x over previous
//
#include <hip/hip_runtime.h>

#define HW    3136   // 56*56
#define HP2   1568   // HW/2 hw-pairs
#define KK    196
#define BCN   256    // B*C
#define KT    7      // k's per main block
#define NKC   28     // KK / KT
#define NSEG  49     // hw-pair segments of 32
#define LOG2E 1.4426950408889634f
// u prescale: log2(e) * 2^23 (Schraudolph domain)
#define PRESCALE (1.4426950408889634f * 8388608.0f)
// centered Schraudolph bias: 127*2^23 - 299487  (max rel err ~ +/-3.6%, zero-mean)
#define SCH_BIAS 1065053729.0f

typedef float v2f __attribute__((ext_vector_type(2)));
typedef int   v2i __attribute__((ext_vector_type(2)));

// ---- Kernel 1: fused prep.
// Blocks [0,784): transpose+prescale u[bc][hw] -> uT2[hw/2][bc] (hw even/odd pairs).
// Blocks [784,956): repack rfs[hw][k] -> rfsP[kc][hp][j][2] ((even,odd) rf pairs).
__global__ __launch_bounds__(256) void rf_prep(const float* __restrict__ u,
                                               const float* __restrict__ rfs,
                                               v2f* __restrict__ uT2,
                                               v2f* __restrict__ rfsP) {
    const int b = blockIdx.x;
    const int t = threadIdx.x;
    if (b < 784) {
        __shared__ float tile[16][65];
        const int h0 = (b % 49) * 64;     // hw tile
        const int b0 = (b / 49) * 16;     // bc tile
        const int c  = t & 63;
        const int r  = t >> 6;            // 0..3
        #pragma unroll
        for (int j = 0; j < 4; ++j)
            tile[r + 4*j][c] = u[(b0 + r + 4*j) * HW + h0 + c] * PRESCALE;
        __syncthreads();
        const int tw  = t & 15;           // bc within tile
        const int hp0 = t >> 4;           // 0..15
        #pragma unroll
        for (int i = 0; i < 2; ++i) {
            const int hp = hp0 + 16 * i;  // 0..31
            v2f v;
            v.x = tile[tw][2*hp];
            v.y = tile[tw][2*hp + 1];
            uT2[(size_t)(h0/2 + hp) * BCN + b0 + tw] = v;
        }
    } else {
        const int idx = (b - 784) * 256 + t;   // kc*HP2 + hpg
        if (idx < NKC * HP2) {
            const int kc  = idx / HP2;
            const int hpg = idx % HP2;
            const float* s0 = rfs + (size_t)(2 * hpg) * KK + kc * KT;
            v2f* d = rfsP + (size_t)idx * KT;
            #pragma unroll
            for (int j = 0; j < KT; ++j) {
                v2f v; v.x = s0[j]; v.y = s0[KK + j];
                d[j] = v;
            }
        }
    }
}

// ---- Kernel 2: main. grid (49 seg, 28 kc), block 256 (lane = bc).
// Preload 32 u-pairs to regs, then packed Schraudolph burst:
// v_pk_fma_f32 + 2x v_cvt_i32_f32 + v_pk_add_f32 per hw-pair per k.
__global__ __launch_bounds__(256) void rf_main(const v2f* __restrict__ uT2,
                                               const v2f* __restrict__ rfsP,
                                               float* __restrict__ part) {
    const int seg = blockIdx.x;            // 0..48
    const int kc  = blockIdx.y;            // 0..27
    const int t   = threadIdx.x;           // bc
    const int h0p = seg * 32;              // hw-pair base

    // Preload all 32 u-pairs (independent loads, all in flight).
    v2f uu[32];
    const v2f* up = uT2 + (size_t)h0p * BCN + t;
    #pragma unroll
    for (int hp = 0; hp < 32; ++hp)
        uu[hp] = up[hp * BCN];

    const v2f* rp = rfsP + ((size_t)kc * HP2 + h0p) * KT;   // wave-uniform, contiguous

    v2f acc[KT];
    #pragma unroll
    for (int j = 0; j < KT; ++j) acc[j] = (v2f){0.f, 0.f};
    const v2f bias = {SCH_BIAS, SCH_BIAS};

    #pragma unroll
    for (int hp = 0; hp < 32; ++hp) {
        const v2f uv = uu[hp];
        #pragma unroll
        for (int j = 0; j < KT; ++j) {
            const v2f rr = rp[hp * KT + j];
            v2f x = uv * rr + bias;                       // v_pk_fma_f32
            v2i n = __builtin_convertvector(x, v2i);      // 2x v_cvt_i32_f32
            acc[j] += *(v2f*)&n;                          // v_pk_add_f32
        }
    }

    float* pp = part + (size_t)(kc * NSEG + seg) * KT * BCN + t;
    #pragma unroll
    for (int j = 0; j < KT; ++j)
        pp[j * BCN] = acc[j].x + acc[j].y;
}

// ---- Kernel 3: reduce 49 segments, p = S/(1+S).
__global__ __launch_bounds__(256) void rf_fin(const float* __restrict__ part,
                                              float* __restrict__ out) {
    const int k = blockIdx.x;    // 0..195
    const int t = threadIdx.x;   // bc
    const int kc = k / KT;
    const int j  = k % KT;
    const float* pb = part + ((size_t)kc * NSEG * KT + j) * BCN + t;
    float s = 0.f;
    #pragma unroll
    for (int sg = 0; sg < NSEG; ++sg)
        s += pb[(size_t)sg * KT * BCN];
    out[(size_t)t * KK + k] = s / (1.0f + s);
}

// ---- Fallback (no workspace): monolithic, lane = k. Known-correct path (real exp2).
__global__ __launch_bounds__(256) void rf_pool_fallback(const float* __restrict__ u,
                                                        const float* __restrict__ rfs,
                                                        float* __restrict__ out) {
    const int grp = blockIdx.x;
    const int tid = threadIdx.x;
    const int bc0 = grp * 8;
    __shared__ __align__(16) float u_lds[8][196];
    float sum[8];
    #pragma unroll
    for (int g = 0; g < 8; ++g) sum[g] = 0.0f;
    for (int base = 0; base < HW; base += 196) {
        __syncthreads();
        if (tid < 196) {
            #pragma unroll
            for (int g = 0; g < 8; ++g)
                u_lds[g][tid] = u[(bc0 + g) * HW + base + tid] * LOG2E;
        }
        __syncthreads();
        if (tid < KK) {
            const float* rp = rfs + (size_t)base * KK + tid;
            for (int h = 0; h < 196; h += 4) {
                float rf0 = rp[(h + 0) * KK];
                float rf1 = rp[(h + 1) * KK];
                float rf2 = rp[(h + 2) * KK];
                float rf3 = rp[(h + 3) * KK];
                #pragma unroll
                for (int g = 0; g < 8; ++g) {
                    float4 ug = *(const float4*)&u_lds[g][h];
                    sum[g] += __builtin_amdgcn_exp2f(ug.x * rf0);
                    sum[g] += __builtin_amdgcn_exp2f(ug.y * rf1);
                    sum[g] += __builtin_amdgcn_exp2f(ug.z * rf2);
                    sum[g] += __builtin_amdgcn_exp2f(ug.w * rf3);
                }
            }
        }
    }
    if (tid < KK) {
        #pragma unroll
        for (int g = 0; g < 8; ++g) {
            float s = sum[g];
            out[(size_t)(bc0 + g) * KK + tid] = s / (s + 1.0f);
        }
    }
}

extern "C" void kernel_launch(void* const* d_in, const int* in_sizes, int n_in,
                              void* d_out, int out_size, void* d_ws, size_t ws_size,
                              hipStream_t stream) {
    const float* u   = (const float*)d_in[0];   // (8,32,56,56) f32
    const float* rfs = (const float*)d_in[1];   // (56,56,196) f32
    float* out = (float*)d_out;                 // (8,32,196) f32

    const size_t uT2_off  = 0;                       // 3.2 MB
    const size_t rfsP_off = 4u << 20;                // @4 MB, 2.46 MB
    const size_t part_off = 8u << 20;                // @8 MB, 9.84 MB
    const size_t need     = part_off + (size_t)NKC * NSEG * KT * BCN * sizeof(float);
    if (ws_size >= need) {
        v2f*   uT2  = (v2f*)((char*)d_ws + uT2_off);
        v2f*   rfsP = (v2f*)((char*)d_ws + rfsP_off);
        float* part = (float*)((char*)d_ws + part_off);
        const int repack_blocks = (NKC * HP2 + 255) / 256;   // 172
        rf_prep<<<784 + repack_blocks, 256, 0, stream>>>(u, rfs, uT2, rfsP);
        rf_main<<<dim3(NSEG, NKC), 256, 0, stream>>>(uT2, rfsP, part);
        rf_fin<<<KK, 256, 0, stream>>>(part, out);
    } else {
        rf_pool_fallback<<<BCN / 8, 256, 0, stream>>>(u, rfs, out);
    }
}

// Round 8
// 32.824 us; speedup vs baseline: 6.4017x; 1.0047x over previous
//
#include <hip/hip_runtime.h>

#define HW    3136   // 56*56
#define KK    196
#define BCN   256    // B*C
#define KT    7      // k's per main block
#define NKC   28     // KK / KT
#define NSEG  98     // hw segments of 32 (16 hw-pairs)
#define LOG2E 1.4426950408889634f
// u prescale: log2(e) * 2^23 (Schraudolph domain)
#define PRESCALE (1.4426950408889634f * 8388608.0f)
// centered Schraudolph bias: 127*2^23 - 299487  (max rel err ~ +/-3.6%, zero-mean)
#define SCH_BIAS 1065053729.0f

typedef float v2f __attribute__((ext_vector_type(2)));

// ---- Kernel 1: fused prep.
// Blocks [0,784): transpose+prescale u[bc][hw] -> uT2[hw/2][bc] (hw even/odd pairs).
// Blocks [784,1127): repack rfs[hw][k] -> rfsT[kc][hw][KT].
__global__ __launch_bounds__(256) void rf_prep(const float* __restrict__ u,
                                               const float* __restrict__ rfs,
                                               v2f* __restrict__ uT2,
                                               float* __restrict__ rfsT) {
    const int b = blockIdx.x;
    const int t = threadIdx.x;
    if (b < 784) {
        __shared__ float tile[16][65];
        const int h0 = (b % 49) * 64;     // hw tile
        const int b0 = (b / 49) * 16;     // bc tile
        const int c  = t & 63;
        const int r  = t >> 6;            // 0..3
        #pragma unroll
        for (int j = 0; j < 4; ++j)
            tile[r + 4*j][c] = u[(b0 + r + 4*j) * HW + h0 + c] * PRESCALE;
        __syncthreads();
        const int tw  = t & 15;           // bc within tile
        const int hp0 = t >> 4;           // 0..15
        #pragma unroll
        for (int i = 0; i < 2; ++i) {
            const int hp = hp0 + 16 * i;  // 0..31
            v2f v;
            v.x = tile[tw][2*hp];
            v.y = tile[tw][2*hp + 1];
            uT2[(size_t)(h0/2 + hp) * BCN + b0 + tw] = v;
        }
    } else {
        const int idx = (b - 784) * 256 + t;   // kc*HW + hw  (28*3136 = 343*256 exact)
        if (idx < NKC * HW) {
            const int kc = idx / HW;
            const int hw = idx % HW;
            const float* s = rfs + (size_t)hw * KK + kc * KT;
            float* d = rfsT + (size_t)idx * KT;
            #pragma unroll
            for (int j = 0; j < KT; ++j) d[j] = s[j];
        }
    }
}

// ---- Kernel 2: main. grid (98 seg, 28 kc), block 256 (lane = bc).
// R5's proven scalar Schraudolph inner math; u loads software-pipelined in
// double-buffered 4-pair windows so VMEM latency hides under VALU.
__global__ __launch_bounds__(256) void rf_main(const v2f* __restrict__ uT2,
                                               const float* __restrict__ rfsT,
                                               float* __restrict__ part) {
    const int seg = blockIdx.x;            // 0..97
    const int kc  = blockIdx.y;            // 0..27
    const int t   = threadIdx.x;           // bc
    const int h0p = seg * 16;              // hw-pair base (16 pairs = 32 hw)

    const v2f*   up = uT2 + (size_t)h0p * BCN + t;
    const float* rp = rfsT + ((size_t)kc * HW + h0p * 2) * KT;   // wave-uniform

    float acc[KT][2];
    #pragma unroll
    for (int j = 0; j < KT; ++j) { acc[j][0] = 0.f; acc[j][1] = 0.f; }

    v2f ubuf[2][4];
    #pragma unroll
    for (int w = 0; w < 4; ++w)
        ubuf[0][w] = up[w * BCN];

    #pragma unroll
    for (int win = 0; win < 4; ++win) {
        const int cur = win & 1;
        // prefetch next window before consuming current
        if (win < 3) {
            #pragma unroll
            for (int w = 0; w < 4; ++w)
                ubuf[cur ^ 1][w] = up[((win + 1) * 4 + w) * BCN];
        }
        #pragma unroll
        for (int w = 0; w < 4; ++w) {
            const int hp = win * 4 + w;
            const v2f uv = ubuf[cur][w];
            #pragma unroll
            for (int j = 0; j < KT; ++j) {
                const float r0 = rp[(2*hp)     * KT + j];
                const float r1 = rp[(2*hp + 1) * KT + j];
                acc[j][0] += __int_as_float((int)fmaf(uv.x, r0, SCH_BIAS));
                acc[j][1] += __int_as_float((int)fmaf(uv.y, r1, SCH_BIAS));
            }
        }
    }

    float* pp = part + (size_t)(kc * NSEG + seg) * KT * BCN + t;
    #pragma unroll
    for (int j = 0; j < KT; ++j)
        pp[j * BCN] = acc[j][0] + acc[j][1];
}

// ---- Kernel 3: reduce 98 segments, p = S/(1+S).
__global__ __launch_bounds__(256) void rf_fin(const float* __restrict__ part,
                                              float* __restrict__ out) {
    const int k = blockIdx.x;    // 0..195
    const int t = threadIdx.x;   // bc
    const int kc = k / KT;
    const int j  = k % KT;
    const float* pb = part + ((size_t)kc * NSEG * KT + j) * BCN + t;
    float s = 0.f;
    #pragma unroll 7
    for (int sg = 0; sg < NSEG; ++sg)
        s += pb[(size_t)sg * KT * BCN];
    out[(size_t)t * KK + k] = s / (1.0f + s);
}

// ---- Fallback (no workspace): monolithic, lane = k. Known-correct path (real exp2).
__global__ __launch_bounds__(256) void rf_pool_fallback(const float* __restrict__ u,
                                                        const float* __restrict__ rfs,
                                                        float* __restrict__ out) {
    const int grp = blockIdx.x;
    const int tid = threadIdx.x;
    const int bc0 = grp * 8;
    __shared__ __align__(16) float u_lds[8][196];
    float sum[8];
    #pragma unroll
    for (int g = 0; g < 8; ++g) sum[g] = 0.0f;
    for (int base = 0; base < HW; base += 196) {
        __syncthreads();
        if (tid < 196) {
            #pragma unroll
            for (int g = 0; g < 8; ++g)
                u_lds[g][tid] = u[(bc0 + g) * HW + base + tid] * LOG2E;
        }
        __syncthreads();
        if (tid < KK) {
            const float* rp = rfs + (size_t)base * KK + tid;
            for (int h = 0; h < 196; h += 4) {
                float rf0 = rp[(h + 0) * KK];
                float rf1 = rp[(h + 1) * KK];
                float rf2 = rp[(h + 2) * KK];
                float rf3 = rp[(h + 3) * KK];
                #pragma unroll
                for (int g = 0; g < 8; ++g) {
                    float4 ug = *(const float4*)&u_lds[g][h];
                    sum[g] += __builtin_amdgcn_exp2f(ug.x * rf0);
                    sum[g] += __builtin_amdgcn_exp2f(ug.y * rf1);
                    sum[g] += __builtin_amdgcn_exp2f(ug.z * rf2);
                    sum[g] += __builtin_amdgcn_exp2f(ug.w * rf3);
                }
            }
        }
    }
    if (tid < KK) {
        #pragma unroll
        for (int g = 0; g < 8; ++g) {
            float s = sum[g];
            out[(size_t)(bc0 + g) * KK + tid] = s / (s + 1.0f);
        }
    }
}

extern "C" void kernel_launch(void* const* d_in, const int* in_sizes, int n_in,
                              void* d_out, int out_size, void* d_ws, size_t ws_size,
                              hipStream_t stream) {
    const float* u   = (const float*)d_in[0];   // (8,32,56,56) f32
    const float* rfs = (const float*)d_in[1];   // (56,56,196) f32
    float* out = (float*)d_out;                 // (8,32,196) f32

    const size_t uT2_off  = 0;                                   // 3.21 MB
    const size_t rfsT_off = 4u << 20;                            // @4 MB, 2.46 MB
    const size_t part_off = 8u << 20;                            // @8 MB, 19.67 MB
    const size_t need     = part_off + (size_t)NKC * NSEG * KT * BCN * sizeof(float);
    if (ws_size >= need) {
        v2f*   uT2  = (v2f*)((char*)d_ws + uT2_off);
        float* rfsT = (float*)((char*)d_ws + rfsT_off);
        float* part = (float*)((char*)d_ws + part_off);
        rf_prep<<<784 + 343, 256, 0, stream>>>(u, rfs, uT2, rfsT);
        rf_main<<<dim3(NSEG, NKC), 256, 0, stream>>>(uT2, rfsT, part);
        rf_fin<<<KK, 256, 0, stream>>>(part, out);
    } else {
        rf_pool_fallback<<<BCN / 8, 256, 0, stream>>>(u, rfs, out);
    }
}

// Round 9
// 29.237 us; speedup vs baseline: 7.1872x; 1.1227x over previous
//
#include <hip/hip_runtime.h>

#define HW    3136   // 56*56
#define HP2   1568   // HW/2 hw-pairs
#define KK    196
#define BCN   256    // B*C
#define KT    7      // k's per main block
#define NKC   28     // KK / KT
#define NSEG  98     // hw segments of 32 hw (16 hw-pairs)
#define SPP   16     // hw-pairs per segment
#define LOG2E 1.4426950408889634f
// u prescale: log2(e) * 2^23 (Schraudolph domain)
#define PRESCALE (1.4426950408889634f * 8388608.0f)
// centered Schraudolph bias: 127*2^23 - 299487  (max rel err ~ +/-3.6%, zero-mean)
#define SCH_BIAS 1065053729.0f

typedef float v2f __attribute__((ext_vector_type(2)));

// ---- Kernel 1: fused prep.
// Blocks [0,784): transpose+prescale u[bc][hw] -> uT2[hw/2][bc] (hw even/odd pairs).
// Blocks [784,956): repack rfs[hw][k] -> rfsP[kc][hp][j] = (rf[2hp][k], rf[2hp+1][k]).
__global__ __launch_bounds__(256) void rf_prep(const float* __restrict__ u,
                                               const float* __restrict__ rfs,
                                               v2f* __restrict__ uT2,
                                               v2f* __restrict__ rfsP) {
    const int b = blockIdx.x;
    const int t = threadIdx.x;
    if (b < 784) {
        __shared__ float tile[16][65];
        const int h0 = (b % 49) * 64;     // hw tile
        const int b0 = (b / 49) * 16;     // bc tile
        const int c  = t & 63;
        const int r  = t >> 6;            // 0..3
        #pragma unroll
        for (int j = 0; j < 4; ++j)
            tile[r + 4*j][c] = u[(b0 + r + 4*j) * HW + h0 + c] * PRESCALE;
        __syncthreads();
        const int tw  = t & 15;           // bc within tile
        const int hp0 = t >> 4;           // 0..15
        #pragma unroll
        for (int i = 0; i < 2; ++i) {
            const int hp = hp0 + 16 * i;  // 0..31
            v2f v;
            v.x = tile[tw][2*hp];
            v.y = tile[tw][2*hp + 1];
            uT2[(size_t)(h0/2 + hp) * BCN + b0 + tw] = v;
        }
    } else {
        const int idx = (b - 784) * 256 + t;   // kc*HP2 + hpg
        if (idx < NKC * HP2) {
            const int kc  = idx / HP2;
            const int hpg = idx % HP2;
            const float* s0 = rfs + (size_t)(2 * hpg) * KK + kc * KT;
            v2f* d = rfsP + (size_t)idx * KT;
            #pragma unroll
            for (int j = 0; j < KT; ++j) {
                v2f v; v.x = s0[j]; v.y = s0[KK + j];
                d[j] = v;
            }
        }
    }
}

// ---- Kernel 2: main. grid (98 seg, 28 kc), block 256 (lane = bc).
// rf tile staged in LDS (896 B) -> inner loop reads rf via ds_read_b64
// (in-order, counted lgkmcnt, pipelineable) instead of out-of-order SMEM
// s_loads that force lgkmcnt(0) drains. Scalar Schraudolph math from R5.
__global__ __launch_bounds__(256) void rf_main(const v2f* __restrict__ uT2,
                                               const v2f* __restrict__ rfsP,
                                               float* __restrict__ part) {
    const int seg = blockIdx.x;            // 0..97
    const int kc  = blockIdx.y;            // 0..27
    const int t   = threadIdx.x;           // bc
    const int h0p = seg * SPP;             // hw-pair base

    __shared__ v2f rf_lds[SPP * KT];       // 112 pairs = 896 B
    if (t < SPP * KT)
        rf_lds[t] = rfsP[((size_t)kc * HP2 + h0p) * KT + t];
    __syncthreads();

    const v2f* up = uT2 + (size_t)h0p * BCN + t;

    float acc[KT][2];
    #pragma unroll
    for (int j = 0; j < KT; ++j) { acc[j][0] = 0.f; acc[j][1] = 0.f; }

    #pragma unroll
    for (int hp = 0; hp < SPP; ++hp) {
        const v2f uv = up[hp * BCN];
        #pragma unroll
        for (int j = 0; j < KT; ++j) {
            const v2f rr = rf_lds[hp * KT + j];   // ds_read_b64, broadcast
            acc[j][0] += __int_as_float((int)fmaf(uv.x, rr.x, SCH_BIAS));
            acc[j][1] += __int_as_float((int)fmaf(uv.y, rr.y, SCH_BIAS));
        }
    }

    float* pp = part + (size_t)(kc * NSEG + seg) * KT * BCN + t;
    #pragma unroll
    for (int j = 0; j < KT; ++j)
        pp[j * BCN] = acc[j][0] + acc[j][1];
}

// ---- Kernel 3: reduce 98 segments, p = S/(1+S). grid (196, 4) x 64 threads.
__global__ __launch_bounds__(64) void rf_fin(const float* __restrict__ part,
                                             float* __restrict__ out) {
    const int k  = blockIdx.x;                      // 0..195
    const int bc = blockIdx.y * 64 + threadIdx.x;   // 0..255
    const int kc = k / KT;
    const int j  = k % KT;
    const float* pb = part + ((size_t)kc * NSEG * KT + j) * BCN + bc;
    float s = 0.f;
    #pragma unroll 14
    for (int sg = 0; sg < NSEG; ++sg)
        s += pb[(size_t)sg * KT * BCN];
    out[(size_t)bc * KK + k] = s / (1.0f + s);
}

// ---- Fallback (no workspace): monolithic, lane = k. Known-correct path (real exp2).
__global__ __launch_bounds__(256) void rf_pool_fallback(const float* __restrict__ u,
                                                        const float* __restrict__ rfs,
                                                        float* __restrict__ out) {
    const int grp = blockIdx.x;
    const int tid = threadIdx.x;
    const int bc0 = grp * 8;
    __shared__ __align__(16) float u_lds[8][196];
    float sum[8];
    #pragma unroll
    for (int g = 0; g < 8; ++g) sum[g] = 0.0f;
    for (int base = 0; base < HW; base += 196) {
        __syncthreads();
        if (tid < 196) {
            #pragma unroll
            for (int g = 0; g < 8; ++g)
                u_lds[g][tid] = u[(bc0 + g) * HW + base + tid] * LOG2E;
        }
        __syncthreads();
        if (tid < KK) {
            const float* rp = rfs + (size_t)base * KK + tid;
            for (int h = 0; h < 196; h += 4) {
                float rf0 = rp[(h + 0) * KK];
                float rf1 = rp[(h + 1) * KK];
                float rf2 = rp[(h + 2) * KK];
                float rf3 = rp[(h + 3) * KK];
                #pragma unroll
                for (int g = 0; g < 8; ++g) {
                    float4 ug = *(const float4*)&u_lds[g][h];
                    sum[g] += __builtin_amdgcn_exp2f(ug.x * rf0);
                    sum[g] += __builtin_amdgcn_exp2f(ug.y * rf1);
                    sum[g] += __builtin_amdgcn_exp2f(ug.z * rf2);
                    sum[g] += __builtin_amdgcn_exp2f(ug.w * rf3);
                }
            }
        }
    }
    if (tid < KK) {
        #pragma unroll
        for (int g = 0; g < 8; ++g) {
            float s = sum[g];
            out[(size_t)(bc0 + g) * KK + tid] = s / (s + 1.0f);
        }
    }
}

extern "C" void kernel_launch(void* const* d_in, const int* in_sizes, int n_in,
                              void* d_out, int out_size, void* d_ws, size_t ws_size,
                              hipStream_t stream) {
    const float* u   = (const float*)d_in[0];   // (8,32,56,56) f32
    const float* rfs = (const float*)d_in[1];   // (56,56,196) f32
    float* out = (float*)d_out;                 // (8,32,196) f32

    const size_t uT2_off  = 0;                                   // 3.21 MB
    const size_t rfsP_off = 4u << 20;                            // @4 MB, 2.46 MB
    const size_t part_off = 8u << 20;                            // @8 MB, 19.67 MB
    const size_t need     = part_off + (size_t)NKC * NSEG * KT * BCN * sizeof(float);
    if (ws_size >= need) {
        v2f*   uT2  = (v2f*)((char*)d_ws + uT2_off);
        v2f*   rfsP = (v2f*)((char*)d_ws + rfsP_off);
        float* part = (float*)((char*)d_ws + part_off);
        const int repack_blocks = (NKC * HP2 + 255) / 256;       // 172
        rf_prep<<<784 + repack_blocks, 256, 0, stream>>>(u, rfs, uT2, rfsP);
        rf_main<<<dim3(NSEG, NKC), 256, 0, stream>>>(uT2, rfsP, part);
        rf_fin<<<dim3(KK, 4), 64, 0, stream>>>(part, out);
    } else {
        rf_pool_fallback<<<BCN / 8, 256, 0, stream>>>(u, rfs, out);
    }
}